// Round 5
// baseline (74.535 us; speedup 1.0000x reference)
//
#include <hip/hip_runtime.h>
#include <math.h>

// DTW loss: B=64, N=512, D=2, L1. Wave64 per batch.
// Round-5: SHORTEN THE SERIAL CHAIN. Model (validated R2-R4): step time ==
// chain ops x ~12cy dep latency. R4: dpp + 8x(min3+add) = 17 ops -> 208cy/step.
// Now lane j owns TWO 4-col blocks: A=[4j,4j+4), B=[256+4j,256+4j+4), block B
// staggered 64 steps. A/B chains are independent -> 9 chain ops/step.
// Col 255->256 wrap: dpp wave_ror:1 of pA[3] feeds lane 0's leftB via the
// dpp `old` operand of wave_shr:1 (timing exact: lane0 B row i at k=i+64
// needs D[i][255], produced by lane 63 at k-1).

typedef float f32x2 __attribute__((ext_vector_type(2)));

constexpr int NSEQ  = 512;
constexpr int BATCH = 64;
constexpr int LANES = 64;
constexpr int FRONT = 128;           // front pad (B prefetch underflow)
constexpr int XSN   = 768;           // FRONT + 640 covers all prefetch idx

__device__ __forceinline__ float dpp_shr1(float v, float old) {
    // lane i <- lane i-1; lane 0 <- old (bound_ctrl=false)
    int r = __builtin_amdgcn_update_dpp(__float_as_int(old), __float_as_int(v),
                                        0x138, 0xF, 0xF, false);
    return __int_as_float(r);
}
__device__ __forceinline__ float dpp_ror1(float v) {
    // wave rotate right by 1: lane i <- lane (i-1)&63; lane 0 <- lane 63
    int r = __builtin_amdgcn_update_dpp(0, __float_as_int(v),
                                        0x13C, 0xF, 0xF, false);
    return __int_as_float(r);
}

__global__ __launch_bounds__(LANES) void dtw_fused(
    const float* __restrict__ pred,    // (B, N, 2) rows (x)
    const float* __restrict__ target,  // (B, N, 2) cols (y)
    float* __restrict__ out,
    float* __restrict__ ws)            // [0..63] per_batch, [64] flag
{
    const int b = blockIdx.x;
    const int j = threadIdx.x;

    __shared__ f32x2 xs[XSN];

    #pragma unroll
    for (int t = 0; t < NSEQ / LANES; ++t) {
        const int idx = t * LANES + j;
        xs[FRONT + idx] = reinterpret_cast<const f32x2*>(pred)[b * NSEQ + idx];
    }
    f32x2 nYA[4], nYB[4];
    #pragma unroll
    for (int c = 0; c < 4; ++c) {
        const f32x2 ya = reinterpret_cast<const f32x2*>(target)[b * NSEQ + 4*j + c];
        nYA[c].x = -ya.x; nYA[c].y = -ya.y;
        const f32x2 yb = reinterpret_cast<const f32x2*>(target)[b * NSEQ + 256 + 4*j + c];
        nYB[c].x = -yb.x; nYB[c].y = -yb.y;
    }
    __syncthreads();   // only barrier

    const float INF = __builtin_inff();
    float pA[4], pB[4];
    #pragma unroll
    for (int c = 0; c < 4; ++c) { pA[c] = INF; pB[c] = INF; }
    float dgA = INF, dgB = INF;

    // k = 0: lane 0, row 0, cols 0..3 cumsum (dgA stays INF).
    if (j == 0) {
        const f32x2 x = xs[FRONT];
        float v = 0.f;
        #pragma unroll
        for (int c = 0; c < 4; ++c) {
            const f32x2 d = x + nYA[c];
            v += fabsf(d.x) + fabsf(d.y);
            pA[c] = v;
        }
    }

    f32x2 xA = xs[FRONT + 1 - j];        // row k=1 for A (pad-covered)
    f32x2 xB = xs[FRONT + 1 - j - 64];   // row k=1 for B (pad-covered)

    // One step: both blocks. Chains independent; INF identities fold row-0
    // cumsum; guards mask prev writes (cndmask) for ramp/drain lanes.
    auto step = [&](int k, bool gA, bool gB) {
        const float leftA = dpp_shr1(pA[3], INF);
        const float rA    = dpp_ror1(pA[3]);        // lane0 <- lane63 col255
        const float leftB = dpp_shr1(pB[3], rA);
        const f32x2 xAn = xs[FRONT + k + 1 - j];        // prefetch next rows
        const f32x2 xBn = xs[FRONT + k + 1 - j - 64];
        float vA[4], vB[4];
        { const f32x2 d = xA + nYA[0];
          vA[0] = fabsf(d.x) + fabsf(d.y) + fminf(fminf(pA[0], dgA), leftA); }
        { const f32x2 d = xB + nYB[0];
          vB[0] = fabsf(d.x) + fabsf(d.y) + fminf(fminf(pB[0], dgB), leftB); }
        float pmA = pA[0], pmB = pB[0];
        #pragma unroll
        for (int c = 1; c < 4; ++c) {
            { const f32x2 d = xA + nYA[c];
              vA[c] = fabsf(d.x) + fabsf(d.y) + fminf(fminf(pA[c], pmA), vA[c-1]);
              pmA = pA[c]; }
            { const f32x2 d = xB + nYB[c];
              vB[c] = fabsf(d.x) + fabsf(d.y) + fminf(fminf(pB[c], pmB), vB[c-1]);
              pmB = pB[c]; }
        }
        if (gA) {
            const bool a = (unsigned)(k - j) < (unsigned)NSEQ;
            #pragma unroll
            for (int c = 0; c < 4; ++c) pA[c] = a ? vA[c] : pA[c];
        } else {
            #pragma unroll
            for (int c = 0; c < 4; ++c) pA[c] = vA[c];
        }
        if (gB) {
            const bool a = (unsigned)(k - j - 64) < (unsigned)NSEQ;
            #pragma unroll
            for (int c = 0; c < 4; ++c) pB[c] = a ? vB[c] : pB[c];
        } else {
            #pragma unroll
            for (int c = 0; c < 4; ++c) pB[c] = vB[c];
        }
        dgA = leftA; dgB = leftB;
        xA = xAn; xB = xBn;
    };

    #pragma unroll 1
    for (int k = 1; k < 128; ++k)   step(k, true, true);    // ramp
    #pragma unroll 2
    for (int k = 128; k < 512; ++k) step(k, false, false);  // HOT: both steady
    #pragma unroll 2
    for (int k = 512; k < 576; ++k) step(k, true, false);   // A drain, B steady
    // B drain only (A finished; lane0 B finished -> plain shr with INF old)
    #pragma unroll 1
    for (int k = 576; k < 639; ++k) {
        const float leftB = dpp_shr1(pB[3], INF);
        const f32x2 xBn = xs[FRONT + k + 1 - j - 64];
        float vB[4];
        { const f32x2 d = xB + nYB[0];
          vB[0] = fabsf(d.x) + fabsf(d.y) + fminf(fminf(pB[0], dgB), leftB); }
        float pmB = pB[0];
        #pragma unroll
        for (int c = 1; c < 4; ++c) {
            const f32x2 d = xB + nYB[c];
            vB[c] = fabsf(d.x) + fabsf(d.y) + fminf(fminf(pB[c], pmB), vB[c-1]);
            pmB = pB[c];
        }
        const bool a = (unsigned)(k - j - 64) < (unsigned)NSEQ;
        #pragma unroll
        for (int c = 0; c < 4; ++c) pB[c] = a ? vB[c] : pB[c];
        dgB = leftB; xB = xBn;
    }

    // ---- fused mean reduction (last block to finish) ----
    float* per_batch = ws;
    unsigned* flag = reinterpret_cast<unsigned*>(ws + BATCH);
    if (j == LANES - 1) per_batch[b] = pB[3];   // D[N-1][N-1]
    __threadfence();
    unsigned old = 0;
    if (j == 0) old = atomicAdd(flag, 1u);
    old = __shfl(old, 0);
    if (old == BATCH - 1) {
        __threadfence();
        float v = per_batch[j];
        #pragma unroll
        for (int off = 32; off >= 1; off >>= 1) v += __shfl_down(v, off);
        if (j == 0) out[0] = v * (1.0f / BATCH);
    }
}

extern "C" void kernel_launch(void* const* d_in, const int* in_sizes, int n_in,
                              void* d_out, int out_size, void* d_ws, size_t ws_size,
                              hipStream_t stream) {
    const float* pred   = (const float*)d_in[0];
    const float* target = (const float*)d_in[1];
    float* out = (float*)d_out;
    float* ws  = (float*)d_ws;

    hipMemsetAsync((char*)d_ws + BATCH * sizeof(float), 0, sizeof(unsigned), stream);
    dtw_fused<<<BATCH, LANES, 0, stream>>>(pred, target, out, ws);
}

// Round 6
// 57.667 us; speedup vs baseline: 1.2925x; 1.2925x over previous
//
#include <hip/hip_runtime.h>
#include <math.h>

// DTW loss: B=64, N=512, D=2, L1. Wave64 per batch, lane j owns cols [8j,8j+8).
// Round-6 model (fits R2-R5): lone-wave time ~= instr/step x ~4.3cy. So: cut
// instructions. P=8 single chain (R4 structure, validated), per-cell 4 instr
// (pk_add + abs-add + min3 + add), 16-step macro blocks with ping-pong row
// rings (no copy movs, branch amortized, big scheduling window), compile-time
// guard split, fused reduction.

typedef float f32x2 __attribute__((ext_vector_type(2)));

constexpr int NSEQ  = 512;
constexpr int BATCH = 64;
constexpr int LANES = 64;
constexpr int P     = 8;
constexpr int FRONT = 64;     // front pad (ramp reads row k-j < 0)
constexpr int XSN   = 656;    // max read idx = FRONT+569+8+7 = 648

__device__ __forceinline__ float dpp_wshr1_inf(float v) {
    // lane i <- lane i-1; lane 0 <- old = +inf (bound_ctrl=false)
    int r = __builtin_amdgcn_update_dpp(0x7F800000, __float_as_int(v),
                                        0x138, 0xF, 0xF, false);
    return __int_as_float(r);
}

__global__ __launch_bounds__(LANES) void dtw_fused(
    const float* __restrict__ pred,    // (B, N, 2) rows (x)
    const float* __restrict__ target,  // (B, N, 2) cols (y)
    float* __restrict__ out,
    float* __restrict__ ws)            // [0..63] per_batch, [64] flag
{
    const int b = blockIdx.x;
    const int j = threadIdx.x;

    __shared__ f32x2 xs[XSN];

    #pragma unroll
    for (int t = 0; t < NSEQ / LANES; ++t) {
        const int idx = t * LANES + j;
        xs[FRONT + idx] = reinterpret_cast<const f32x2*>(pred)[b * NSEQ + idx];
    }
    f32x2 nY[P];
    #pragma unroll
    for (int c = 0; c < P; ++c) {
        const f32x2 y = reinterpret_cast<const f32x2*>(target)[b * NSEQ + j * P + c];
        nY[c].x = -y.x; nY[c].y = -y.y;
    }
    __syncthreads();   // only barrier

    const float INF = __builtin_inff();
    float prev[P];
    #pragma unroll
    for (int c = 0; c < P; ++c) prev[c] = INF;
    float dg = INF;    // D[i-1][8j-1]; lane 0: INF forever

    // k = 0: lane 0, row 0, cumsum over its 8 cols (dg stays INF).
    if (j == 0) {
        const f32x2 x = xs[FRONT];
        float v = 0.f;
        #pragma unroll
        for (int c = 0; c < P; ++c) {
            const f32x2 d = x + nY[c];
            v += fabsf(d.x) + fabsf(d.y);
            prev[c] = v;
        }
    }

    // One step: v[c] = cost_c + min3(up=prev[c], diag=prev[c-1]|dg, left-chain).
    // INF identities fold row-0 cumsum in; guard masks prev[] commits.
    auto step = [&](f32x2 x, int k, bool guard) {
        float cost[P];
        #pragma unroll
        for (int c = 0; c < P; ++c) {
            const f32x2 d = x + nY[c];           // v_pk_add_f32
            cost[c] = fabsf(d.x) + fabsf(d.y);   // v_add_f32 |a|,|b|
        }
        const float left = dpp_wshr1_inf(prev[P - 1]);
        float v[P];
        v[0] = cost[0] + fminf(fminf(prev[0], dg), left);
        float pm = prev[0];
        #pragma unroll
        for (int c = 1; c < P; ++c) {
            v[c] = cost[c] + fminf(fminf(prev[c], pm), v[c - 1]);
            pm = prev[c];
        }
        if (guard) {
            const bool act = (unsigned)(k - j) < (unsigned)NSEQ;
            #pragma unroll
            for (int c = 0; c < P; ++c) prev[c] = act ? v[c] : prev[c];
        } else {
            #pragma unroll
            for (int c = 0; c < P; ++c) prev[c] = v[c];
        }
        dg = left;
    };

    // 8 steps using ring Rr (rows k0..k0+7); prefetch rows k0+8..k0+15 into Nn.
    auto block8 = [&](int k0, f32x2 (&Rr)[8], f32x2 (&Nn)[8], bool guard) {
        #pragma unroll
        for (int d = 0; d < 8; ++d) Nn[d] = xs[FRONT + k0 + 8 + d - j];
        #pragma unroll
        for (int d = 0; d < 8; ++d) step(Rr[d], k0 + d, guard);
    };

    f32x2 R[8], N[8];
    #pragma unroll
    for (int d = 0; d < 8; ++d) R[d] = xs[FRONT + 1 + d - j];   // rows 1..8

    // 36 macro-blocks of 16 steps cover k = 1..576; ping-pong R/N.
    #pragma unroll 1
    for (int m = 0; m < 4; ++m) {          // ramp: k = 1..64
        const int k0 = 1 + m * 16;
        block8(k0, R, N, true);
        block8(k0 + 8, N, R, true);
    }
    #pragma unroll 1
    for (int m = 0; m < 27; ++m) {         // steady: k = 65..496
        const int k0 = 65 + m * 16;
        block8(k0, R, N, false);
        block8(k0 + 8, N, R, false);
    }
    #pragma unroll 1
    for (int m = 0; m < 5; ++m) {          // drain: k = 497..576
        const int k0 = 497 + m * 16;
        block8(k0, R, N, true);
        block8(k0 + 8, N, R, true);
    }

    // ---- fused mean reduction (last block to finish) ----
    float* per_batch = ws;
    unsigned* flag = reinterpret_cast<unsigned*>(ws + BATCH);
    if (j == LANES - 1) per_batch[b] = prev[P - 1];   // D[N-1][N-1]
    __threadfence();
    unsigned old = 0;
    if (j == 0) old = atomicAdd(flag, 1u);
    old = __shfl(old, 0);
    if (old == BATCH - 1) {
        __threadfence();
        float v = per_batch[j];
        #pragma unroll
        for (int off = 32; off >= 1; off >>= 1) v += __shfl_down(v, off);
        if (j == 0) out[0] = v * (1.0f / BATCH);
    }
}

extern "C" void kernel_launch(void* const* d_in, const int* in_sizes, int n_in,
                              void* d_out, int out_size, void* d_ws, size_t ws_size,
                              hipStream_t stream) {
    const float* pred   = (const float*)d_in[0];
    const float* target = (const float*)d_in[1];
    float* out = (float*)d_out;
    float* ws  = (float*)d_ws;

    hipMemsetAsync((char*)d_ws + BATCH * sizeof(float), 0, sizeof(unsigned), stream);
    dtw_fused<<<BATCH, LANES, 0, stream>>>(pred, target, out, ws);
}